// Round 8
// baseline (751.678 us; speedup 1.0000x reference)
//
#include <hip/hip_runtime.h>
#include <stdint.h>

// GCN, DIM=1. Build: count_chunks (per-chunk bin histograms) -> chunk_scan
// (exact per-chunk cursors) -> place1 (single-pass bin scatter; bins =
// 16K-dst-bucket x 4 src-blocks = 248) -> wplace (per-bin 256-src window sort,
// 1 block/bin, direct LDS-hist place). Layers: barrier-free scan per half-bin,
// uint4 edge reads, L1-local gathers, LDS atomics into 64KB acc (2 blocks/CU);
// grid-stride reduce fuses bias/ReLU (+readout).

static constexpr int NGRAPHS  = 256;
static constexpr int TB       = 256;
static constexpr int TB_P     = 512;    // place block
static constexpr int NCHUNK   = 256;    // edge chunks (count & place)
static constexpr int TB_A     = 1024;   // agg block
static constexpr int DSTB_LOG = 14;
static constexpr int DSTB     = 1 << DSTB_LOG;   // 16384 dst nodes per bucket
static constexpr int NSB_LOG  = 2;               // 4 src blocks
static constexpr int SRCB_LOG = 18;              // 256K srcs per block
static constexpr uint32_t SRCMASK = (1u << SRCB_LOG) - 1;
static constexpr int MAXB     = 256;             // max bins
static constexpr int WLOG     = 8;               // 256-src windows
static constexpr int NW       = 1 << (SRCB_LOG - WLOG);  // 1024 windows/src-block

// ---------------- common ----------------

__global__ void node_init(const float4* __restrict__ x,
                          const float* __restrict__ W0n,
                          const float* __restrict__ W0s,
                          float* __restrict__ xw0,
                          float* __restrict__ s0,
                          int n_nodes) {
    int n = blockIdx.x * blockDim.x + threadIdx.x;
    if (n >= n_nodes) return;
    float4 a = x[2 * n];
    float4 b = x[2 * n + 1];
    float xn = a.x * W0n[0] + a.y * W0n[1] + a.z * W0n[2] + a.w * W0n[3] +
               b.x * W0n[4] + b.y * W0n[5] + b.z * W0n[6] + b.w * W0n[7];
    float xs = a.x * W0s[0] + a.y * W0s[1] + a.z * W0s[2] + a.w * W0s[3] +
               b.x * W0s[4] + b.y * W0s[5] + b.z * W0s[6] + b.w * W0s[7];
    xw0[n] = xn;
    s0[n] = xs;
}

__global__ void head(const float* __restrict__ hg,
                     const float* __restrict__ fc1_w,
                     const float* __restrict__ fc1_b,
                     const float* __restrict__ out_w,
                     const float* __restrict__ out_b,
                     float* __restrict__ out) {
    int gph = threadIdx.x;
    if (gph >= NGRAPHS) return;
    float hv = hg[gph];
    float o0 = out_b[0], o1 = out_b[1], o2 = out_b[2], o3 = out_b[3];
#pragma unroll
    for (int j = 0; j < 8; ++j) {
        float z = (hv * fc1_w[j] + fc1_b[j]) * 1000.0f;
        float sg = 1.0f / (1.0f + expf(-z));
        o0 += sg * out_w[j * 4 + 0];
        o1 += sg * out_w[j * 4 + 1];
        o2 += sg * out_w[j * 4 + 2];
        o3 += sg * out_w[j * 4 + 3];
    }
    o0 = fmaxf(o0, 0.0f); o1 = fmaxf(o1, 0.0f);
    o2 = fmaxf(o2, 0.0f); o3 = fmaxf(o3, 0.0f);
    float m = fmaxf(fmaxf(o0, o1), fmaxf(o2, o3));
    float s = expf(o0 - m) + expf(o1 - m) + expf(o2 - m) + expf(o3 - m);
    float l = logf(s);
    out[gph * 4 + 0] = o0 - m - l;
    out[gph * 4 + 1] = o1 - m - l;
    out[gph * 4 + 2] = o2 - m - l;
    out[gph * 4 + 3] = o3 - m - l;
}

__device__ __forceinline__ int bin1_of(int d, int s) {
    return ((d >> DSTB_LOG) << NSB_LOG) | ((unsigned)s >> SRCB_LOG);
}
__device__ __forceinline__ uint32_t rec_of(int d, int s) {
    return ((uint32_t)(d & (DSTB - 1)) << SRCB_LOG) | ((uint32_t)s & SRCMASK);
}

// ---------------- build ----------------

// Per-chunk histograms. Chunk decomposition MUST match place1's.
__global__ void count_chunks(const int* __restrict__ src,
                             const int* __restrict__ dst,
                             int n_edges, int nbins,
                             int* __restrict__ chunk_hist) {
    __shared__ int hist[MAXB];
    for (int i = threadIdx.x; i < MAXB; i += blockDim.x) hist[i] = 0;
    __syncthreads();
    const int nq = n_edges >> 2;
    const int per = (nq + NCHUNK - 1) / NCHUNK;
    const int b0 = blockIdx.x * per;
    const int b1 = min(b0 + per, nq);
    const bool last = (blockIdx.x == NCHUNK - 1);
    const int4* s4 = (const int4*)src;
    const int4* d4 = (const int4*)dst;
    for (int q = b0 + threadIdx.x; q < b1; q += blockDim.x) {
        int4 d = d4[q]; int4 s = s4[q];
        atomicAdd(&hist[bin1_of(d.x, s.x)], 1);
        atomicAdd(&hist[bin1_of(d.y, s.y)], 1);
        atomicAdd(&hist[bin1_of(d.z, s.z)], 1);
        atomicAdd(&hist[bin1_of(d.w, s.w)], 1);
    }
    if (last) {
        for (int e = (nq << 2) + threadIdx.x; e < n_edges; e += blockDim.x)
            atomicAdd(&hist[bin1_of(dst[e], src[e])], 1);
    }
    __syncthreads();
    for (int i = threadIdx.x; i < MAXB; i += blockDim.x)
        chunk_hist[blockIdx.x * MAXB + i] = hist[i];
}

// One block: bin offsets + exact per-(chunk,bin) cursors.
__global__ void chunk_scan(const int* __restrict__ chunk_hist, int nbins,
                           int* __restrict__ offs, int* __restrict__ cursors) {
    __shared__ int lds[MAXB];
    const int b = threadIdx.x;
    int total = 0;
    if (b < nbins)
        for (int c = 0; c < NCHUNK; ++c) total += chunk_hist[c * MAXB + b];
    lds[b] = total;
    __syncthreads();
    for (int off = 1; off < MAXB; off <<= 1) {
        int v = (b >= off) ? lds[b - off] : 0;
        __syncthreads();
        lds[b] += v;
        __syncthreads();
    }
    int excl = lds[b] - total;
    offs[b] = excl;
    if (b == MAXB - 1) offs[MAXB] = lds[MAXB - 1];
    if (b < nbins) {
        int run = excl;
        for (int c = 0; c < NCHUNK; ++c) {
            cursors[c * MAXB + b] = run;
            run += chunk_hist[c * MAXB + b];
        }
    }
}

// Single-pass bin scatter with precomputed cursors.
__global__ void place1(const int* __restrict__ src,
                       const int* __restrict__ dst,
                       int n_edges, int nbins,
                       const int* __restrict__ cursors,
                       uint32_t* __restrict__ sorted) {
    __shared__ int cur[MAXB];
    for (int i = threadIdx.x; i < MAXB; i += blockDim.x)
        cur[i] = cursors[blockIdx.x * MAXB + i];
    __syncthreads();
    const int nq = n_edges >> 2;
    const int per = (nq + NCHUNK - 1) / NCHUNK;
    const int b0 = blockIdx.x * per;
    const int b1 = min(b0 + per, nq);
    const bool last = (blockIdx.x == NCHUNK - 1);
    const int4* s4 = (const int4*)src;
    const int4* d4 = (const int4*)dst;
    for (int q = b0 + threadIdx.x; q < b1; q += blockDim.x) {
        int4 d = d4[q]; int4 s = s4[q];
        int p0 = atomicAdd(&cur[bin1_of(d.x, s.x)], 1);
        int p1 = atomicAdd(&cur[bin1_of(d.y, s.y)], 1);
        int p2 = atomicAdd(&cur[bin1_of(d.z, s.z)], 1);
        int p3 = atomicAdd(&cur[bin1_of(d.w, s.w)], 1);
        sorted[p0] = rec_of(d.x, s.x);
        sorted[p1] = rec_of(d.y, s.y);
        sorted[p2] = rec_of(d.z, s.z);
        sorted[p3] = rec_of(d.w, s.w);
    }
    if (last) {
        for (int e = (nq << 2) + threadIdx.x; e < n_edges; e += blockDim.x) {
            int pos = atomicAdd(&cur[bin1_of(dst[e], src[e])], 1);
            sorted[pos] = rec_of(dst[e], src[e]);
        }
    }
}

// Per-bin window sort: direct place, 1 block per bin.
__global__ __launch_bounds__(1024) void wplace(const uint32_t* __restrict__ s1,
                                               const int* __restrict__ offs,
                                               uint32_t* __restrict__ s2) {
    __shared__ int hist[NW];
    __shared__ int incl[NW];
    __shared__ int cur[NW];
    const int bin = blockIdx.x;
    const int tid = threadIdx.x;
    const int beg = offs[bin], end = offs[bin + 1];
    hist[tid] = 0;
    __syncthreads();
    // phase A: window histogram (vectorized)
    {
        int vbeg = min((beg + 3) & ~3, end);
        int vend = (vbeg < end) ? (end & ~3) : vbeg;
        for (int e = beg + tid; e < vbeg; e += 1024)
            atomicAdd(&hist[(s1[e] >> WLOG) & (NW - 1)], 1);
        const uint4* s1q = (const uint4*)s1;
        for (int q = (vbeg >> 2) + tid; q < (vend >> 2); q += 1024) {
            uint4 r = s1q[q];
            atomicAdd(&hist[(r.x >> WLOG) & (NW - 1)], 1);
            atomicAdd(&hist[(r.y >> WLOG) & (NW - 1)], 1);
            atomicAdd(&hist[(r.z >> WLOG) & (NW - 1)], 1);
            atomicAdd(&hist[(r.w >> WLOG) & (NW - 1)], 1);
        }
        for (int e = max(vend, beg) + tid; e < end; e += 1024)
            atomicAdd(&hist[(s1[e] >> WLOG) & (NW - 1)], 1);
    }
    __syncthreads();
    // exclusive scan
    incl[tid] = hist[tid];
    __syncthreads();
    for (int off = 1; off < NW; off <<= 1) {
        int v = (tid >= off) ? incl[tid - off] : 0;
        __syncthreads();
        incl[tid] += v;
        __syncthreads();
    }
    cur[tid] = incl[tid] - hist[tid];
    __syncthreads();
    // phase C: place (reads are L2-hot after phase A)
    for (int e = beg + tid; e < end; e += 1024) {
        uint32_t r = s1[e];
        int p = atomicAdd(&cur[(r >> WLOG) & (NW - 1)], 1);
        s2[beg + p] = r;
    }
}

// ---------------- per-layer aggregation ----------------

__global__ __launch_bounds__(TB_A) void agg2(const uint32_t* __restrict__ s2,
                                             const int* __restrict__ offs,
                                             const float* __restrict__ gsrc,
                                             float* __restrict__ partial) {
    __shared__ float acc[DSTB];   // 64 KB -> 2 blocks/CU
    const int b = blockIdx.x;
    const int bin = b >> 1;
    const int half = b & 1;
    const int tid = threadIdx.x;
    for (int i = tid; i < DSTB; i += TB_A) acc[i] = 0.0f;
    __syncthreads();
    const int beg = offs[bin], end = offs[bin + 1];
    const int len = end - beg;
    int hl = ((len + 1) >> 1 + 0);
    hl = (hl + 3) & ~3;
    const int mid = min(beg + hl, end);
    const int e0 = half ? mid : beg;
    const int e1 = half ? end : mid;
    const float* hs = gsrc + ((size_t)(bin & ((1 << NSB_LOG) - 1)) << SRCB_LOG);

    int vbeg = min((e0 + 3) & ~3, e1);
    int vend = (vbeg < e1) ? (e1 & ~3) : vbeg;
    for (int e = e0 + tid; e < vbeg; e += TB_A) {
        uint32_t r = s2[e];
        atomicAdd(&acc[r >> SRCB_LOG], hs[r & SRCMASK]);
    }
    const uint4* s2q = (const uint4*)s2;
#pragma unroll 2
    for (int q = (vbeg >> 2) + tid; q < (vend >> 2); q += TB_A) {
        uint4 r = s2q[q];
        float v0 = hs[r.x & SRCMASK];
        float v1 = hs[r.y & SRCMASK];
        float v2 = hs[r.z & SRCMASK];
        float v3 = hs[r.w & SRCMASK];
        atomicAdd(&acc[r.x >> SRCB_LOG], v0);
        atomicAdd(&acc[r.y >> SRCB_LOG], v1);
        atomicAdd(&acc[r.z >> SRCB_LOG], v2);
        atomicAdd(&acc[r.w >> SRCB_LOG], v3);
    }
    for (int e = max(vend, e0) + tid; e < e1; e += TB_A) {
        uint32_t r = s2[e];
        atomicAdd(&acc[r >> SRCB_LOG], hs[r & SRCMASK]);
    }
    __syncthreads();
    float* o = partial + (size_t)b * DSTB;
    for (int i = tid; i < DSTB; i += TB_A) o[i] = acc[i];
}

// ---------------- reduce (8 partial rows per dst bucket) + node update ----------------

__global__ void reduce_l0(const float* __restrict__ partial,
                          const float* __restrict__ s0,
                          const float* __restrict__ b0,
                          float* __restrict__ h_out, int n_nodes) {
    const float bb = b0[0];
    const int stride = gridDim.x * blockDim.x;
    for (int n = blockIdx.x * blockDim.x + threadIdx.x; n < n_nodes; n += stride) {
        const float* p = partial + ((size_t)(n >> DSTB_LOG) << (3 + DSTB_LOG)) + (n & (DSTB - 1));
        float v = 0.0f;
#pragma unroll
        for (int m = 0; m < 8; ++m) v += p[(size_t)m << DSTB_LOG];
        h_out[n] = fmaxf(v + bb + s0[n], 0.0f);
    }
}

__global__ void reduce_lk(const float* __restrict__ partial,
                          const float* __restrict__ h_in,
                          const float* __restrict__ Wkn,
                          const float* __restrict__ bk,
                          const float* __restrict__ Wks,
                          int li, float* __restrict__ h_out, int n_nodes) {
    const float wn = Wkn[li], bb = bk[li], ws = Wks[li];
    const int stride = gridDim.x * blockDim.x;
    for (int n = blockIdx.x * blockDim.x + threadIdx.x; n < n_nodes; n += stride) {
        const float* p = partial + ((size_t)(n >> DSTB_LOG) << (3 + DSTB_LOG)) + (n & (DSTB - 1));
        float v = 0.0f;
#pragma unroll
        for (int m = 0; m < 8; ++m) v += p[(size_t)m << DSTB_LOG];
        h_out[n] = fmaxf(wn * v + bb + ws * h_in[n], 0.0f);
    }
}

__global__ void reduce_last(const float* __restrict__ partial,
                            const float* __restrict__ h_in,
                            const int* __restrict__ graph_ids,
                            const float* __restrict__ Wkn,
                            const float* __restrict__ bk,
                            const float* __restrict__ Wks,
                            int li, float* __restrict__ hg, int n_nodes) {
    const float wn = Wkn[li], bb = bk[li], ws = Wks[li];
    const int stride = gridDim.x * blockDim.x;
    const int nloop = (n_nodes + stride - 1) / stride * stride;  // uniform trip count
    for (int n = blockIdx.x * blockDim.x + threadIdx.x; n < nloop; n += stride) {
        float val = 0.0f;
        int g = -1;
        if (n < n_nodes) {
            const float* p = partial + ((size_t)(n >> DSTB_LOG) << (3 + DSTB_LOG)) + (n & (DSTB - 1));
            float v = 0.0f;
#pragma unroll
            for (int m = 0; m < 8; ++m) v += p[(size_t)m << DSTB_LOG];
            val = fmaxf(wn * v + bb + ws * h_in[n], 0.0f);
            g = graph_ids[n];
        }
        int g0 = __shfl(g, 0);
        unsigned long long same = __ballot(g == g0);
        if (same == ~0ULL) {
            for (int o = 32; o > 0; o >>= 1) val += __shfl_down(val, o);
            if ((threadIdx.x & 63) == 0 && g >= 0) atomicAdd(&hg[g], val);
        } else if (g >= 0) {
            atomicAdd(&hg[g], val);
        }
    }
}

// ---------------- fallback: global atomics ----------------

__global__ void edge_scatter(const int4* __restrict__ src4,
                             const int4* __restrict__ dst4,
                             const float* __restrict__ val,
                             float* __restrict__ agg, int nquads) {
    int t = blockIdx.x * blockDim.x + threadIdx.x;
    if (t >= nquads) return;
    int4 s = src4[t]; int4 d = dst4[t];
    atomicAdd(&agg[d.x], val[s.x]);
    atomicAdd(&agg[d.y], val[s.y]);
    atomicAdd(&agg[d.z], val[s.z]);
    atomicAdd(&agg[d.w], val[s.w]);
}

__global__ void node_l0(float* __restrict__ agg, const float* __restrict__ s0,
                        const float* __restrict__ b0, float* __restrict__ h, int n_nodes) {
    int n = blockIdx.x * blockDim.x + threadIdx.x;
    if (n >= n_nodes) return;
    h[n] = fmaxf(agg[n] + b0[0] + s0[n], 0.0f);
    agg[n] = 0.0f;
}

__global__ void node_lk(float* __restrict__ agg, float* __restrict__ h,
                        const float* __restrict__ Wkn, const float* __restrict__ bk,
                        const float* __restrict__ Wks, int li, int n_nodes) {
    int n = blockIdx.x * blockDim.x + threadIdx.x;
    if (n >= n_nodes) return;
    float v = Wkn[li] * agg[n] + bk[li] + Wks[li] * h[n];
    h[n] = fmaxf(v, 0.0f);
    agg[n] = 0.0f;
}

__global__ void node_l3_readout(const float* __restrict__ agg, const float* __restrict__ h,
                                const int* __restrict__ graph_ids,
                                const float* __restrict__ Wkn, const float* __restrict__ bk,
                                const float* __restrict__ Wks, float* __restrict__ hg,
                                int n_nodes) {
    int n = blockIdx.x * blockDim.x + threadIdx.x;
    float val = 0.0f;
    int g = -1;
    if (n < n_nodes) {
        val = fmaxf(Wkn[2] * agg[n] + bk[2] + Wks[2] * h[n], 0.0f);
        g = graph_ids[n];
    }
    int g0 = __shfl(g, 0);
    unsigned long long same = __ballot(g == g0);
    if (same == ~0ULL) {
        for (int o = 32; o > 0; o >>= 1) val += __shfl_down(val, o);
        if ((threadIdx.x & 63) == 0 && g >= 0) atomicAdd(&hg[g], val);
    } else if (g >= 0) {
        atomicAdd(&hg[g], val);
    }
}

// ---------------- launch ----------------

extern "C" void kernel_launch(void* const* d_in, const int* in_sizes, int n_in,
                              void* d_out, int out_size, void* d_ws, size_t ws_size,
                              hipStream_t stream) {
    const float* x        = (const float*)d_in[0];
    const int*   src      = (const int*)d_in[1];
    const int*   dst      = (const int*)d_in[2];
    const int*   graphids = (const int*)d_in[3];
    const float* W0n   = (const float*)d_in[5];
    const float* b0    = (const float*)d_in[6];
    const float* W0s   = (const float*)d_in[7];
    const float* Wkn   = (const float*)d_in[8];
    const float* bk    = (const float*)d_in[9];
    const float* Wks   = (const float*)d_in[10];
    const float* fc1_w = (const float*)d_in[11];
    const float* fc1_b = (const float*)d_in[12];
    const float* out_w = (const float*)d_in[13];
    const float* out_b = (const float*)d_in[14];
    float* out = (float*)d_out;

    const int n_nodes = in_sizes[0] / 8;
    const int n_edges = in_sizes[1];
    const int nbd     = (n_nodes + DSTB - 1) >> DSTB_LOG;          // dst buckets
    const int nbins   = nbd << NSB_LOG;                            // x 4 src blocks
    const int node_blocks = (n_nodes + TB - 1) / TB;

    const size_t E4    = (size_t)n_edges * 4;
    const size_t NBP   = (size_t)(1 << 20) * sizeof(float);        // padded node array (4MB)
    const size_t part_bytes = (size_t)2 * nbins * DSTB * sizeof(float);
    const size_t ov_need    = 4 * NBP + part_bytes;
    const size_t ov_bytes   = (ov_need > E4) ? ov_need : E4;
    const size_t tail_bytes = (MAXB + 1) * sizeof(int) + NGRAPHS * sizeof(float) + 256;
    const size_t need_full  = E4 + ov_bytes + tail_bytes;
    // chunk_hist + cursors overlay the head of s2 (dead before wplace writes s2)
    const size_t overlay_bytes = (size_t)2 * NCHUNK * MAXB * sizeof(int);

    const bool shape_ok = (nbins <= MAXB) && (n_nodes <= (1 << 20)) &&
                          (n_edges >= 4) && (E4 >= overlay_bytes);

    if (shape_ok && ws_size >= need_full) {
        // ---- FULL path ----
        char* ws = (char*)d_ws;
        uint32_t* s2 = (uint32_t*)ws;                      ws += E4;
        char* ov = ws;                                     ws += ov_bytes;
        uint32_t* s1 = (uint32_t*)ov;                      // build-time alias
        float* xw0 = (float*)(ov);
        float* s0  = (float*)(ov + NBP);
        float* h_a = (float*)(ov + 2 * NBP);
        float* h_b = (float*)(ov + 3 * NBP);
        float* partial = (float*)(ov + 4 * NBP);
        int* offs   = (int*)ws;                            ws += (MAXB + 1) * sizeof(int);
        float* hg   = (float*)ws;
        int* chunk_hist = (int*)s2;                        // overlay in s2 head
        int* cursors    = chunk_hist + NCHUNK * MAXB;

        hipMemsetAsync(hg, 0, NGRAPHS * sizeof(float), stream);

        count_chunks<<<NCHUNK, TB_P, 0, stream>>>(src, dst, n_edges, nbins, chunk_hist);
        chunk_scan<<<1, MAXB, 0, stream>>>(chunk_hist, nbins, offs, cursors);
        place1<<<NCHUNK, TB_P, 0, stream>>>(src, dst, n_edges, nbins, cursors, s1);
        wplace<<<nbins, 1024, 0, stream>>>(s1, offs, s2);
        // s1 dead: overlay node arrays + partials
        node_init<<<node_blocks, TB, 0, stream>>>((const float4*)x, W0n, W0s, xw0, s0, n_nodes);

        agg2<<<2 * nbins, TB_A, 0, stream>>>(s2, offs, xw0, partial);
        reduce_l0<<<1024, 256, 0, stream>>>(partial, s0, b0, h_a, n_nodes);

        agg2<<<2 * nbins, TB_A, 0, stream>>>(s2, offs, h_a, partial);
        reduce_lk<<<1024, 256, 0, stream>>>(partial, h_a, Wkn, bk, Wks, 0, h_b, n_nodes);

        agg2<<<2 * nbins, TB_A, 0, stream>>>(s2, offs, h_b, partial);
        reduce_lk<<<1024, 256, 0, stream>>>(partial, h_b, Wkn, bk, Wks, 1, h_a, n_nodes);

        agg2<<<2 * nbins, TB_A, 0, stream>>>(s2, offs, h_a, partial);
        reduce_last<<<1024, 256, 0, stream>>>(partial, h_a, graphids, Wkn, bk, Wks, 2, hg, n_nodes);

        head<<<1, TB, 0, stream>>>(hg, fc1_w, fc1_b, out_w, out_b, out);
    } else {
        // ---- fallback: global atomics ----
        const size_t NB = (size_t)n_nodes * sizeof(float);
        char* ws   = (char*)d_ws;
        float* agg = (float*)(ws);
        float* h   = (float*)(ws + NB);
        float* xw0 = (float*)(ws + 2 * NB);
        float* s0  = (float*)(ws + 3 * NB);
        float* hg  = (float*)(ws + 4 * NB);
        const int nquads = n_edges >> 2;
        const int edge_blocks = (nquads + TB - 1) / TB;

        hipMemsetAsync(agg, 0, NB, stream);
        hipMemsetAsync(hg, 0, NGRAPHS * sizeof(float), stream);

        node_init<<<node_blocks, TB, 0, stream>>>((const float4*)x, W0n, W0s, xw0, s0, n_nodes);
        edge_scatter<<<edge_blocks, TB, 0, stream>>>((const int4*)src, (const int4*)dst, xw0, agg, nquads);
        node_l0<<<node_blocks, TB, 0, stream>>>(agg, s0, b0, h, n_nodes);
        for (int li = 0; li < 2; ++li) {
            edge_scatter<<<edge_blocks, TB, 0, stream>>>((const int4*)src, (const int4*)dst, h, agg, nquads);
            node_lk<<<node_blocks, TB, 0, stream>>>(agg, h, Wkn, bk, Wks, li, n_nodes);
        }
        edge_scatter<<<edge_blocks, TB, 0, stream>>>((const int4*)src, (const int4*)dst, h, agg, nquads);
        node_l3_readout<<<node_blocks, TB, 0, stream>>>(agg, h, graphids, Wkn, bk, Wks, hg, n_nodes);
        head<<<1, TB, 0, stream>>>(hg, fc1_w, fc1_b, out_w, out_b, out);
    }
}

// Round 9
// 677.798 us; speedup vs baseline: 1.1090x; 1.1090x over previous
//
#include <hip/hip_runtime.h>
#include <stdint.h>

// GCN, DIM=1. Build: count_chunks (per-chunk bin histograms) -> chunk_scan
// (exact per-chunk cursors) -> place1 (single-pass bin scatter; bins =
// 16K-dst-bucket x 4 src-blocks = 248) -> wplace (per-bin 1024-src window
// sort, 256 windows -> only 16KB of active write lines per block, single
// writeback). Layers: barrier-free scan per half-bin, uint4 edge reads,
// L1-local gathers (4KB window slice), LDS atomics into 64KB acc
// (2 blocks/CU); grid-stride reduce fuses bias/ReLU (+readout).

static constexpr int NGRAPHS  = 256;
static constexpr int TB       = 256;
static constexpr int TB_P     = 512;    // place block
static constexpr int NCHUNK   = 256;    // edge chunks (count & place)
static constexpr int TB_A     = 1024;   // agg block
static constexpr int DSTB_LOG = 14;
static constexpr int DSTB     = 1 << DSTB_LOG;   // 16384 dst nodes per bucket
static constexpr int NSB_LOG  = 2;               // 4 src blocks
static constexpr int SRCB_LOG = 18;              // 256K srcs per block
static constexpr uint32_t SRCMASK = (1u << SRCB_LOG) - 1;
static constexpr int MAXB     = 256;             // max bins
static constexpr int WLOG     = 10;              // 1024-src windows
static constexpr int NW       = 1 << (SRCB_LOG - WLOG);  // 256 windows/src-block

// ---------------- common ----------------

__global__ void node_init(const float4* __restrict__ x,
                          const float* __restrict__ W0n,
                          const float* __restrict__ W0s,
                          float* __restrict__ xw0,
                          float* __restrict__ s0,
                          int n_nodes) {
    int n = blockIdx.x * blockDim.x + threadIdx.x;
    if (n >= n_nodes) return;
    float4 a = x[2 * n];
    float4 b = x[2 * n + 1];
    float xn = a.x * W0n[0] + a.y * W0n[1] + a.z * W0n[2] + a.w * W0n[3] +
               b.x * W0n[4] + b.y * W0n[5] + b.z * W0n[6] + b.w * W0n[7];
    float xs = a.x * W0s[0] + a.y * W0s[1] + a.z * W0s[2] + a.w * W0s[3] +
               b.x * W0s[4] + b.y * W0s[5] + b.z * W0s[6] + b.w * W0s[7];
    xw0[n] = xn;
    s0[n] = xs;
}

__global__ void head(const float* __restrict__ hg,
                     const float* __restrict__ fc1_w,
                     const float* __restrict__ fc1_b,
                     const float* __restrict__ out_w,
                     const float* __restrict__ out_b,
                     float* __restrict__ out) {
    int gph = threadIdx.x;
    if (gph >= NGRAPHS) return;
    float hv = hg[gph];
    float o0 = out_b[0], o1 = out_b[1], o2 = out_b[2], o3 = out_b[3];
#pragma unroll
    for (int j = 0; j < 8; ++j) {
        float z = (hv * fc1_w[j] + fc1_b[j]) * 1000.0f;
        float sg = 1.0f / (1.0f + expf(-z));
        o0 += sg * out_w[j * 4 + 0];
        o1 += sg * out_w[j * 4 + 1];
        o2 += sg * out_w[j * 4 + 2];
        o3 += sg * out_w[j * 4 + 3];
    }
    o0 = fmaxf(o0, 0.0f); o1 = fmaxf(o1, 0.0f);
    o2 = fmaxf(o2, 0.0f); o3 = fmaxf(o3, 0.0f);
    float m = fmaxf(fmaxf(o0, o1), fmaxf(o2, o3));
    float s = expf(o0 - m) + expf(o1 - m) + expf(o2 - m) + expf(o3 - m);
    float l = logf(s);
    out[gph * 4 + 0] = o0 - m - l;
    out[gph * 4 + 1] = o1 - m - l;
    out[gph * 4 + 2] = o2 - m - l;
    out[gph * 4 + 3] = o3 - m - l;
}

__device__ __forceinline__ int bin1_of(int d, int s) {
    return ((d >> DSTB_LOG) << NSB_LOG) | ((unsigned)s >> SRCB_LOG);
}
__device__ __forceinline__ uint32_t rec_of(int d, int s) {
    return ((uint32_t)(d & (DSTB - 1)) << SRCB_LOG) | ((uint32_t)s & SRCMASK);
}

// ---------------- build ----------------

// Per-chunk histograms. Chunk decomposition MUST match place1's.
__global__ void count_chunks(const int* __restrict__ src,
                             const int* __restrict__ dst,
                             int n_edges, int nbins,
                             int* __restrict__ chunk_hist) {
    __shared__ int hist[MAXB];
    for (int i = threadIdx.x; i < MAXB; i += blockDim.x) hist[i] = 0;
    __syncthreads();
    const int nq = n_edges >> 2;
    const int per = (nq + NCHUNK - 1) / NCHUNK;
    const int b0 = blockIdx.x * per;
    const int b1 = min(b0 + per, nq);
    const bool last = (blockIdx.x == NCHUNK - 1);
    const int4* s4 = (const int4*)src;
    const int4* d4 = (const int4*)dst;
    for (int q = b0 + threadIdx.x; q < b1; q += blockDim.x) {
        int4 d = d4[q]; int4 s = s4[q];
        atomicAdd(&hist[bin1_of(d.x, s.x)], 1);
        atomicAdd(&hist[bin1_of(d.y, s.y)], 1);
        atomicAdd(&hist[bin1_of(d.z, s.z)], 1);
        atomicAdd(&hist[bin1_of(d.w, s.w)], 1);
    }
    if (last) {
        for (int e = (nq << 2) + threadIdx.x; e < n_edges; e += blockDim.x)
            atomicAdd(&hist[bin1_of(dst[e], src[e])], 1);
    }
    __syncthreads();
    for (int i = threadIdx.x; i < MAXB; i += blockDim.x)
        chunk_hist[blockIdx.x * MAXB + i] = hist[i];
}

// One block: bin offsets + exact per-(chunk,bin) cursors.
__global__ void chunk_scan(const int* __restrict__ chunk_hist, int nbins,
                           int* __restrict__ offs, int* __restrict__ cursors) {
    __shared__ int lds[MAXB];
    const int b = threadIdx.x;
    int total = 0;
    if (b < nbins)
        for (int c = 0; c < NCHUNK; ++c) total += chunk_hist[c * MAXB + b];
    lds[b] = total;
    __syncthreads();
    for (int off = 1; off < MAXB; off <<= 1) {
        int v = (b >= off) ? lds[b - off] : 0;
        __syncthreads();
        lds[b] += v;
        __syncthreads();
    }
    int excl = lds[b] - total;
    offs[b] = excl;
    if (b == MAXB - 1) offs[MAXB] = lds[MAXB - 1];
    if (b < nbins) {
        int run = excl;
        for (int c = 0; c < NCHUNK; ++c) {
            cursors[c * MAXB + b] = run;
            run += chunk_hist[c * MAXB + b];
        }
    }
}

// Single-pass bin scatter with precomputed cursors.
__global__ void place1(const int* __restrict__ src,
                       const int* __restrict__ dst,
                       int n_edges, int nbins,
                       const int* __restrict__ cursors,
                       uint32_t* __restrict__ sorted) {
    __shared__ int cur[MAXB];
    for (int i = threadIdx.x; i < MAXB; i += blockDim.x)
        cur[i] = cursors[blockIdx.x * MAXB + i];
    __syncthreads();
    const int nq = n_edges >> 2;
    const int per = (nq + NCHUNK - 1) / NCHUNK;
    const int b0 = blockIdx.x * per;
    const int b1 = min(b0 + per, nq);
    const bool last = (blockIdx.x == NCHUNK - 1);
    const int4* s4 = (const int4*)src;
    const int4* d4 = (const int4*)dst;
    for (int q = b0 + threadIdx.x; q < b1; q += blockDim.x) {
        int4 d = d4[q]; int4 s = s4[q];
        int p0 = atomicAdd(&cur[bin1_of(d.x, s.x)], 1);
        int p1 = atomicAdd(&cur[bin1_of(d.y, s.y)], 1);
        int p2 = atomicAdd(&cur[bin1_of(d.z, s.z)], 1);
        int p3 = atomicAdd(&cur[bin1_of(d.w, s.w)], 1);
        sorted[p0] = rec_of(d.x, s.x);
        sorted[p1] = rec_of(d.y, s.y);
        sorted[p2] = rec_of(d.z, s.z);
        sorted[p3] = rec_of(d.w, s.w);
    }
    if (last) {
        for (int e = (nq << 2) + threadIdx.x; e < n_edges; e += blockDim.x) {
            int pos = atomicAdd(&cur[bin1_of(dst[e], src[e])], 1);
            sorted[pos] = rec_of(dst[e], src[e]);
        }
    }
}

// Per-bin window sort: direct place, 1 block per bin. 256 windows ->
// only 16KB of active output cache lines per block (single writeback).
__global__ __launch_bounds__(1024) void wplace(const uint32_t* __restrict__ s1,
                                               const int* __restrict__ offs,
                                               uint32_t* __restrict__ s2) {
    __shared__ int hist[NW];
    __shared__ int incl[NW];
    __shared__ int cur[NW];
    const int bin = blockIdx.x;
    const int tid = threadIdx.x;
    const int beg = offs[bin], end = offs[bin + 1];
    if (tid < NW) hist[tid] = 0;
    __syncthreads();
    // phase A: window histogram (vectorized)
    {
        int vbeg = min((beg + 3) & ~3, end);
        int vend = (vbeg < end) ? (end & ~3) : vbeg;
        for (int e = beg + tid; e < vbeg; e += 1024)
            atomicAdd(&hist[(s1[e] >> WLOG) & (NW - 1)], 1);
        const uint4* s1q = (const uint4*)s1;
        for (int q = (vbeg >> 2) + tid; q < (vend >> 2); q += 1024) {
            uint4 r = s1q[q];
            atomicAdd(&hist[(r.x >> WLOG) & (NW - 1)], 1);
            atomicAdd(&hist[(r.y >> WLOG) & (NW - 1)], 1);
            atomicAdd(&hist[(r.z >> WLOG) & (NW - 1)], 1);
            atomicAdd(&hist[(r.w >> WLOG) & (NW - 1)], 1);
        }
        for (int e = max(vend, beg) + tid; e < end; e += 1024)
            atomicAdd(&hist[(s1[e] >> WLOG) & (NW - 1)], 1);
    }
    __syncthreads();
    // exclusive scan (first NW threads)
    if (tid < NW) incl[tid] = hist[tid];
    __syncthreads();
    for (int off = 1; off < NW; off <<= 1) {
        int v = (tid < NW && tid >= off) ? incl[tid - off] : 0;
        __syncthreads();
        if (tid < NW) incl[tid] += v;
        __syncthreads();
    }
    if (tid < NW) cur[tid] = incl[tid] - hist[tid];
    __syncthreads();
    // phase C: place (reads are L2-hot after phase A)
    for (int e = beg + tid; e < end; e += 1024) {
        uint32_t r = s1[e];
        int p = atomicAdd(&cur[(r >> WLOG) & (NW - 1)], 1);
        s2[beg + p] = r;
    }
}

// ---------------- per-layer aggregation ----------------

__global__ __launch_bounds__(TB_A) void agg2(const uint32_t* __restrict__ s2,
                                             const int* __restrict__ offs,
                                             const float* __restrict__ gsrc,
                                             float* __restrict__ partial) {
    __shared__ float acc[DSTB];   // 64 KB -> 2 blocks/CU
    const int b = blockIdx.x;
    const int bin = b >> 1;
    const int half = b & 1;
    const int tid = threadIdx.x;
    for (int i = tid; i < DSTB; i += TB_A) acc[i] = 0.0f;
    __syncthreads();
    const int beg = offs[bin], end = offs[bin + 1];
    const int len = end - beg;
    int hl = (len + 1) >> 1;
    hl = (hl + 3) & ~3;
    const int mid = min(beg + hl, end);
    const int e0 = half ? mid : beg;
    const int e1 = half ? end : mid;
    const float* hs = gsrc + ((size_t)(bin & ((1 << NSB_LOG) - 1)) << SRCB_LOG);

    int vbeg = min((e0 + 3) & ~3, e1);
    int vend = (vbeg < e1) ? (e1 & ~3) : vbeg;
    for (int e = e0 + tid; e < vbeg; e += TB_A) {
        uint32_t r = s2[e];
        atomicAdd(&acc[r >> SRCB_LOG], hs[r & SRCMASK]);
    }
    const uint4* s2q = (const uint4*)s2;
#pragma unroll 2
    for (int q = (vbeg >> 2) + tid; q < (vend >> 2); q += TB_A) {
        uint4 r = s2q[q];
        float v0 = hs[r.x & SRCMASK];
        float v1 = hs[r.y & SRCMASK];
        float v2 = hs[r.z & SRCMASK];
        float v3 = hs[r.w & SRCMASK];
        atomicAdd(&acc[r.x >> SRCB_LOG], v0);
        atomicAdd(&acc[r.y >> SRCB_LOG], v1);
        atomicAdd(&acc[r.z >> SRCB_LOG], v2);
        atomicAdd(&acc[r.w >> SRCB_LOG], v3);
    }
    for (int e = max(vend, e0) + tid; e < e1; e += TB_A) {
        uint32_t r = s2[e];
        atomicAdd(&acc[r >> SRCB_LOG], hs[r & SRCMASK]);
    }
    __syncthreads();
    float* o = partial + (size_t)b * DSTB;
    for (int i = tid; i < DSTB; i += TB_A) o[i] = acc[i];
}

// ---------------- reduce (8 partial rows per dst bucket) + node update ----------------

__global__ void reduce_l0(const float* __restrict__ partial,
                          const float* __restrict__ s0,
                          const float* __restrict__ b0,
                          float* __restrict__ h_out, int n_nodes) {
    const float bb = b0[0];
    const int stride = gridDim.x * blockDim.x;
    for (int n = blockIdx.x * blockDim.x + threadIdx.x; n < n_nodes; n += stride) {
        const float* p = partial + ((size_t)(n >> DSTB_LOG) << (3 + DSTB_LOG)) + (n & (DSTB - 1));
        float v = 0.0f;
#pragma unroll
        for (int m = 0; m < 8; ++m) v += p[(size_t)m << DSTB_LOG];
        h_out[n] = fmaxf(v + bb + s0[n], 0.0f);
    }
}

__global__ void reduce_lk(const float* __restrict__ partial,
                          const float* __restrict__ h_in,
                          const float* __restrict__ Wkn,
                          const float* __restrict__ bk,
                          const float* __restrict__ Wks,
                          int li, float* __restrict__ h_out, int n_nodes) {
    const float wn = Wkn[li], bb = bk[li], ws = Wks[li];
    const int stride = gridDim.x * blockDim.x;
    for (int n = blockIdx.x * blockDim.x + threadIdx.x; n < n_nodes; n += stride) {
        const float* p = partial + ((size_t)(n >> DSTB_LOG) << (3 + DSTB_LOG)) + (n & (DSTB - 1));
        float v = 0.0f;
#pragma unroll
        for (int m = 0; m < 8; ++m) v += p[(size_t)m << DSTB_LOG];
        h_out[n] = fmaxf(wn * v + bb + ws * h_in[n], 0.0f);
    }
}

__global__ void reduce_last(const float* __restrict__ partial,
                            const float* __restrict__ h_in,
                            const int* __restrict__ graph_ids,
                            const float* __restrict__ Wkn,
                            const float* __restrict__ bk,
                            const float* __restrict__ Wks,
                            int li, float* __restrict__ hg, int n_nodes) {
    const float wn = Wkn[li], bb = bk[li], ws = Wks[li];
    const int stride = gridDim.x * blockDim.x;
    const int nloop = (n_nodes + stride - 1) / stride * stride;  // uniform trip count
    for (int n = blockIdx.x * blockDim.x + threadIdx.x; n < nloop; n += stride) {
        float val = 0.0f;
        int g = -1;
        if (n < n_nodes) {
            const float* p = partial + ((size_t)(n >> DSTB_LOG) << (3 + DSTB_LOG)) + (n & (DSTB - 1));
            float v = 0.0f;
#pragma unroll
            for (int m = 0; m < 8; ++m) v += p[(size_t)m << DSTB_LOG];
            val = fmaxf(wn * v + bb + ws * h_in[n], 0.0f);
            g = graph_ids[n];
        }
        int g0 = __shfl(g, 0);
        unsigned long long same = __ballot(g == g0);
        if (same == ~0ULL) {
            for (int o = 32; o > 0; o >>= 1) val += __shfl_down(val, o);
            if ((threadIdx.x & 63) == 0 && g >= 0) atomicAdd(&hg[g], val);
        } else if (g >= 0) {
            atomicAdd(&hg[g], val);
        }
    }
}

// ---------------- fallback: global atomics ----------------

__global__ void edge_scatter(const int4* __restrict__ src4,
                             const int4* __restrict__ dst4,
                             const float* __restrict__ val,
                             float* __restrict__ agg, int nquads) {
    int t = blockIdx.x * blockDim.x + threadIdx.x;
    if (t >= nquads) return;
    int4 s = src4[t]; int4 d = dst4[t];
    atomicAdd(&agg[d.x], val[s.x]);
    atomicAdd(&agg[d.y], val[s.y]);
    atomicAdd(&agg[d.z], val[s.z]);
    atomicAdd(&agg[d.w], val[s.w]);
}

__global__ void node_l0(float* __restrict__ agg, const float* __restrict__ s0,
                        const float* __restrict__ b0, float* __restrict__ h, int n_nodes) {
    int n = blockIdx.x * blockDim.x + threadIdx.x;
    if (n >= n_nodes) return;
    h[n] = fmaxf(agg[n] + b0[0] + s0[n], 0.0f);
    agg[n] = 0.0f;
}

__global__ void node_lk(float* __restrict__ agg, float* __restrict__ h,
                        const float* __restrict__ Wkn, const float* __restrict__ bk,
                        const float* __restrict__ Wks, int li, int n_nodes) {
    int n = blockIdx.x * blockDim.x + threadIdx.x;
    if (n >= n_nodes) return;
    float v = Wkn[li] * agg[n] + bk[li] + Wks[li] * h[n];
    h[n] = fmaxf(v, 0.0f);
    agg[n] = 0.0f;
}

__global__ void node_l3_readout(const float* __restrict__ agg, const float* __restrict__ h,
                                const int* __restrict__ graph_ids,
                                const float* __restrict__ Wkn, const float* __restrict__ bk,
                                const float* __restrict__ Wks, float* __restrict__ hg,
                                int n_nodes) {
    int n = blockIdx.x * blockDim.x + threadIdx.x;
    float val = 0.0f;
    int g = -1;
    if (n < n_nodes) {
        val = fmaxf(Wkn[2] * agg[n] + bk[2] + Wks[2] * h[n], 0.0f);
        g = graph_ids[n];
    }
    int g0 = __shfl(g, 0);
    unsigned long long same = __ballot(g == g0);
    if (same == ~0ULL) {
        for (int o = 32; o > 0; o >>= 1) val += __shfl_down(val, o);
        if ((threadIdx.x & 63) == 0 && g >= 0) atomicAdd(&hg[g], val);
    } else if (g >= 0) {
        atomicAdd(&hg[g], val);
    }
}

// ---------------- launch ----------------

extern "C" void kernel_launch(void* const* d_in, const int* in_sizes, int n_in,
                              void* d_out, int out_size, void* d_ws, size_t ws_size,
                              hipStream_t stream) {
    const float* x        = (const float*)d_in[0];
    const int*   src      = (const int*)d_in[1];
    const int*   dst      = (const int*)d_in[2];
    const int*   graphids = (const int*)d_in[3];
    const float* W0n   = (const float*)d_in[5];
    const float* b0    = (const float*)d_in[6];
    const float* W0s   = (const float*)d_in[7];
    const float* Wkn   = (const float*)d_in[8];
    const float* bk    = (const float*)d_in[9];
    const float* Wks   = (const float*)d_in[10];
    const float* fc1_w = (const float*)d_in[11];
    const float* fc1_b = (const float*)d_in[12];
    const float* out_w = (const float*)d_in[13];
    const float* out_b = (const float*)d_in[14];
    float* out = (float*)d_out;

    const int n_nodes = in_sizes[0] / 8;
    const int n_edges = in_sizes[1];
    const int nbd     = (n_nodes + DSTB - 1) >> DSTB_LOG;          // dst buckets
    const int nbins   = nbd << NSB_LOG;                            // x 4 src blocks
    const int node_blocks = (n_nodes + TB - 1) / TB;

    const size_t E4    = (size_t)n_edges * 4;
    const size_t NBP   = (size_t)(1 << 20) * sizeof(float);        // padded node array (4MB)
    const size_t part_bytes = (size_t)2 * nbins * DSTB * sizeof(float);
    const size_t ov_need    = 4 * NBP + part_bytes;
    const size_t ov_bytes   = (ov_need > E4) ? ov_need : E4;
    const size_t tail_bytes = (MAXB + 1) * sizeof(int) + NGRAPHS * sizeof(float) + 256;
    const size_t need_full  = E4 + ov_bytes + tail_bytes;
    // chunk_hist + cursors overlay the head of s2 (dead before wplace writes s2)
    const size_t overlay_bytes = (size_t)2 * NCHUNK * MAXB * sizeof(int);

    const bool shape_ok = (nbins <= MAXB) && (n_nodes <= (1 << 20)) &&
                          (n_edges >= 4) && (E4 >= overlay_bytes);

    if (shape_ok && ws_size >= need_full) {
        // ---- FULL path ----
        char* ws = (char*)d_ws;
        uint32_t* s2 = (uint32_t*)ws;                      ws += E4;
        char* ov = ws;                                     ws += ov_bytes;
        uint32_t* s1 = (uint32_t*)ov;                      // build-time alias
        float* xw0 = (float*)(ov);
        float* s0  = (float*)(ov + NBP);
        float* h_a = (float*)(ov + 2 * NBP);
        float* h_b = (float*)(ov + 3 * NBP);
        float* partial = (float*)(ov + 4 * NBP);
        int* offs   = (int*)ws;                            ws += (MAXB + 1) * sizeof(int);
        float* hg   = (float*)ws;
        int* chunk_hist = (int*)s2;                        // overlay in s2 head
        int* cursors    = chunk_hist + NCHUNK * MAXB;

        hipMemsetAsync(hg, 0, NGRAPHS * sizeof(float), stream);

        count_chunks<<<NCHUNK, TB_P, 0, stream>>>(src, dst, n_edges, nbins, chunk_hist);
        chunk_scan<<<1, MAXB, 0, stream>>>(chunk_hist, nbins, offs, cursors);
        place1<<<NCHUNK, TB_P, 0, stream>>>(src, dst, n_edges, nbins, cursors, s1);
        wplace<<<nbins, 1024, 0, stream>>>(s1, offs, s2);
        // s1 dead: overlay node arrays + partials
        node_init<<<node_blocks, TB, 0, stream>>>((const float4*)x, W0n, W0s, xw0, s0, n_nodes);

        agg2<<<2 * nbins, TB_A, 0, stream>>>(s2, offs, xw0, partial);
        reduce_l0<<<1024, 256, 0, stream>>>(partial, s0, b0, h_a, n_nodes);

        agg2<<<2 * nbins, TB_A, 0, stream>>>(s2, offs, h_a, partial);
        reduce_lk<<<1024, 256, 0, stream>>>(partial, h_a, Wkn, bk, Wks, 0, h_b, n_nodes);

        agg2<<<2 * nbins, TB_A, 0, stream>>>(s2, offs, h_b, partial);
        reduce_lk<<<1024, 256, 0, stream>>>(partial, h_b, Wkn, bk, Wks, 1, h_a, n_nodes);

        agg2<<<2 * nbins, TB_A, 0, stream>>>(s2, offs, h_a, partial);
        reduce_last<<<1024, 256, 0, stream>>>(partial, h_a, graphids, Wkn, bk, Wks, 2, hg, n_nodes);

        head<<<1, TB, 0, stream>>>(hg, fc1_w, fc1_b, out_w, out_b, out);
    } else {
        // ---- fallback: global atomics ----
        const size_t NB = (size_t)n_nodes * sizeof(float);
        char* ws   = (char*)d_ws;
        float* agg = (float*)(ws);
        float* h   = (float*)(ws + NB);
        float* xw0 = (float*)(ws + 2 * NB);
        float* s0  = (float*)(ws + 3 * NB);
        float* hg  = (float*)(ws + 4 * NB);
        const int nquads = n_edges >> 2;
        const int edge_blocks = (nquads + TB - 1) / TB;

        hipMemsetAsync(agg, 0, NB, stream);
        hipMemsetAsync(hg, 0, NGRAPHS * sizeof(float), stream);

        node_init<<<node_blocks, TB, 0, stream>>>((const float4*)x, W0n, W0s, xw0, s0, n_nodes);
        edge_scatter<<<edge_blocks, TB, 0, stream>>>((const int4*)src, (const int4*)dst, xw0, agg, nquads);
        node_l0<<<node_blocks, TB, 0, stream>>>(agg, s0, b0, h, n_nodes);
        for (int li = 0; li < 2; ++li) {
            edge_scatter<<<edge_blocks, TB, 0, stream>>>((const int4*)src, (const int4*)dst, h, agg, nquads);
            node_lk<<<node_blocks, TB, 0, stream>>>(agg, h, Wkn, bk, Wks, li, n_nodes);
        }
        edge_scatter<<<edge_blocks, TB, 0, stream>>>((const int4*)src, (const int4*)dst, h, agg, nquads);
        node_l3_readout<<<node_blocks, TB, 0, stream>>>(agg, h, graphids, Wkn, bk, Wks, hg, n_nodes);
        head<<<1, TB, 0, stream>>>(hg, fc1_w, fc1_b, out_w, out_b, out);
    }
}